// Round 1
// baseline (160.035 us; speedup 1.0000x reference)
//
#include <hip/hip_runtime.h>

namespace {
constexpr int IMG_W = 512, IMG_H = 512;
constexpr int TW = 32, TH = 64;
constexpr int IN_H = TH + 10;           // 74 staged rows
constexpr int IN_UNITS = 22;            // 44 px = 22 v4f units per row
constexpr int P1_TASKS = IN_H * IN_UNITS;   // 1628
constexpr float C1c = 0.01f * 0.01f;
constexpr float C2c = 0.03f * 0.03f;

constexpr float GW[11] = {
    1.0283799e-03f, 7.5987582e-03f, 3.6000773e-02f, 1.0936069e-01f,
    2.1300554e-01f, 2.6601172e-01f, 2.1300554e-01f, 1.0936069e-01f,
    3.6000773e-02f, 7.5987582e-03f, 1.0283799e-03f
};

using v2f = __attribute__((ext_vector_type(2))) float;
using v4f = __attribute__((ext_vector_type(4))) float;

// In-place packed FMA, weight in SGPR pair: acc += w * a.
__device__ __forceinline__ void pkfma(v2f& acc, v2f w, v2f a) {
    asm("v_pk_fma_f32 %0, %1, %2, %0" : "+v"(acc) : "s"(w), "v"(a));
}
__device__ __forceinline__ v2f pkmul(v2f a, v2f b) {
    v2f d;
    asm("v_pk_mul_f32 %0, %1, %2" : "=v"(d) : "v"(a), "v"(b));
    return d;
}
__device__ __forceinline__ v2f bcast(float w) { v2f r; r.x = w; r.y = w; return r; }

// Unified plane: stride 32 v4f + rotate swizzle (col+row)&31.
// Bank-quad = (col+row) mod 8 -> every access class below spreads lanes
// uniformly over the 8 bank-quads (conflict-free at b128 minimum rounds).
__device__ __forceinline__ int pidx(int row, int col) {
    return row * 32 + ((col + row) & 31);
}
}

// One 74x32-v4f plane (37888 B) serves both roles (time-sliced by barriers):
//   raw:  unit c of row r = pixels {x0e+2c, x0e+2c+1} packed {a0,b0,a1,b1}
//   h:    col c of row r  = (mu1, mu2, ss=conv(x^2+y^2), xy=conv(x*y))
// 37.9 KB -> 4 blocks/CU. (256,4): allocator cap 128 VGPR.
__global__ __launch_bounds__(256, 4) void ssim_tile_kernel(
        const float* __restrict__ img1, const float* __restrict__ img2,
        double* __restrict__ acc)
{
    __shared__ v4f plane[IN_H * 32];
    __shared__ float wred[4];

    const int tid = threadIdx.x;
    const size_t base = (size_t)blockIdx.z * (IMG_W * IMG_H);
    const float* p1 = img1 + base;
    const float* p2 = img2 + base;
    const int x0e = blockIdx.x * TW - 6;    // even; window cols = pixels x0e..x0e+43
    const int y0  = blockIdx.y * TH - 5;

    // ---- Phase 1: global -> LDS, 2 pixels/thread, 74x22=1628 units, 7 rounds ----
    {
        int r   = tid / 22;
        int cf2 = tid - r * 22;
        int goff = (y0 + r) * IMG_W + x0e + 2 * cf2;
        const bool interior =
            blockIdx.x > 0 && blockIdx.x < gridDim.x - 1 &&
            blockIdx.y > 0 && blockIdx.y < gridDim.y - 1;
        if (interior) {
#pragma unroll
            for (int i = 0; i < 7; ++i) {
                if (i < 6 || tid < P1_TASKS - 6 * 256) {     // 92
                    const float2 a = *(const float2*)&p1[goff];
                    const float2 b = *(const float2*)&p2[goff];
                    v4f q; q.x = a.x; q.y = b.x; q.z = a.y; q.w = b.y;
                    plane[pidx(r, cf2)] = q;
                }
                const bool wrap = cf2 + 14 >= 22;
                cf2  += wrap ? -8 : 14;
                r    += wrap ? 12 : 11;
                goff += wrap ? 12 * IMG_W - 16 : 11 * IMG_W + 28;
            }
        } else {
#pragma unroll
            for (int i = 0; i < 7; ++i) {
                if (i < 6 || tid < P1_TASKS - 6 * 256) {
                    const int gy = y0 + r;
                    const int gx = x0e + 2 * cf2;
                    float a0 = 0.f, a1 = 0.f, b0 = 0.f, b1 = 0.f;
                    if (gy >= 0 && gy < IMG_H) {
                        if (gx >= 0 && gx < IMG_W)         { a0 = p1[goff];     b0 = p2[goff]; }
                        if (gx + 1 >= 0 && gx + 1 < IMG_W) { a1 = p1[goff + 1]; b1 = p2[goff + 1]; }
                    }
                    v4f q; q.x = a0; q.y = b0; q.z = a1; q.w = b1;
                    plane[pidx(r, cf2)] = q;
                }
                const bool wrap = cf2 + 14 >= 22;
                cf2  += wrap ? -8 : 14;
                r    += wrap ? 12 : 11;
                goff += wrap ? 12 * IMG_W - 16 : 11 * IMG_W + 28;
            }
        }
    }
    __syncthreads();

    // ---- Phase 2: horizontal 11-tap, scatter form ----
    // 74 rows x 4 col-groups (8 outputs each) = 296 tasks; all threads do task A,
    // tid<40 also do task B (rows 64..73). Window col k (v2f) = pixel x0e+8g+k;
    // output j taps t = k - j - 1.
    v2f muA[8], sxA[8], muB[8], sxB[8];
    const int rA = tid >> 2;
    const int gA = tid & 3;
    const bool hasB = tid < 40;
    const int rB = 64 + (tid >> 2);

    auto hconv = [&](int r2, int g2, v2f* mu8, v2f* sx8) {
#pragma unroll
        for (int j = 0; j < 8; ++j) { mu8[j] = bcast(0.f); sx8[j] = bcast(0.f); }
        const int rowb = r2 * 32;
        const int cb   = g2 * 4 + r2;            // rotation base
#pragma unroll
        for (int m = 0; m < 10; ++m) {
            const v4f q = plane[rowb + ((cb + m) & 31)];
#pragma unroll
            for (int half = 0; half < 2; ++half) {
                const int k = 2 * m + half;
                v2f v;
                v.x = half ? q.z : q.x;
                v.y = half ? q.w : q.y;
                const v2f a2 = pkmul(v, v);
                v2f sx;                          // {x^2+y^2, x*y}
                sx.x = a2.x + a2.y;
                sx.y = v.x * v.y;
#pragma unroll
                for (int j = 0; j < 8; ++j) {
                    const int t = k - j - 1;
                    if (t >= 0 && t < 11) {
                        const v2f w2 = bcast(GW[t]);
                        pkfma(mu8[j], w2, v);
                        pkfma(sx8[j], w2, sx);
                    }
                }
            }
        }
    };

    hconv(rA, gA, muA, sxA);
    if (hasB) hconv(rB, gA, muB, sxB);
    __syncthreads();            // all raw-plane reads done; safe to overwrite
#pragma unroll
    for (int j = 0; j < 8; ++j) {
        v4f q;
        q.x = muA[j].x; q.y = muA[j].y;
        q.z = sxA[j].x; q.w = sxA[j].y;
        plane[pidx(rA, 8 * gA + j)] = q;
    }
    if (hasB) {
#pragma unroll
        for (int j = 0; j < 8; ++j) {
            v4f q;
            q.x = muB[j].x; q.y = muB[j].y;
            q.z = sxB[j].x; q.w = sxB[j].y;
            plane[pidx(rB, 8 * gA + j)] = q;
        }
    }
    __syncthreads();

    // ---- Phase 3: vertical 11-tap + SSIM, scatter form, 8 rows/thread ----
    const int c3 = tid & 31;
    const int rb = (tid >> 5) * 8;
    v2f mu8[8], sx8[8];
#pragma unroll
    for (int j = 0; j < 8; ++j) { mu8[j] = bcast(0.f); sx8[j] = bcast(0.f); }
#pragma unroll
    for (int k = 0; k < 18; ++k) {
        const v4f q = plane[pidx(rb + k, c3)];
        v2f hm; hm.x = q.x; hm.y = q.y;
        v2f hx; hx.x = q.z; hx.y = q.w;
#pragma unroll
        for (int j = 0; j < 8; ++j) {
            const int t = k - j;
            if (t >= 0 && t < 11) {
                const v2f w2 = bcast(GW[t]);
                pkfma(mu8[j], w2, hm);
                pkfma(sx8[j], w2, hx);
            }
        }
    }
    float lsum = 0.f;
#pragma unroll
    for (int j = 0; j < 8; ++j) {
        const v2f musq = pkmul(mu8[j], mu8[j]);       // {mu1^2, mu2^2}
        const float mu12 = mu8[j].x * mu8[j].y;
        const float sden = musq.x + musq.y;           // mu1^2 + mu2^2
        const float s12v = sx8[j].y - mu12;           // sigma12
        const float ssum = sx8[j].x - sden;           // sigma1^2 + sigma2^2
        const float num = (2.f * mu12 + C1c) * (2.f * s12v + C2c);
        const float den = (sden + C1c) * (ssum + C2c);
        lsum += __fdividef(num, den);
    }

    // ---- Phase 4: block reduce -> double atomic into 256 ws slots ----
#pragma unroll
    for (int off = 32; off > 0; off >>= 1)
        lsum += __shfl_down(lsum, off, 64);
    if ((tid & 63) == 0) wred[tid >> 6] = lsum;
    __syncthreads();
    if (tid == 0) {
        const int bid = (blockIdx.z * gridDim.y + blockIdx.y) * gridDim.x + blockIdx.x;
        unsafeAtomicAdd(&acc[bid & 255],
                        (double)(wred[0] + wred[1] + wred[2] + wred[3]));
    }
}

__global__ __launch_bounds__(256) void ssim_final_kernel(
        const double* __restrict__ acc, float* __restrict__ out, double inv_total)
{
    const int tid = threadIdx.x;
    double a = acc[tid];
#pragma unroll
    for (int off = 32; off > 0; off >>= 1)
        a += __shfl_down(a, off, 64);
    __shared__ double ws[4];
    if ((tid & 63) == 0) ws[tid >> 6] = a;
    __syncthreads();
    if (tid == 0)
        out[0] = (float)((ws[0] + ws[1] + ws[2] + ws[3]) * inv_total);
}

extern "C" void kernel_launch(void* const* d_in, const int* in_sizes, int n_in,
                              void* d_out, int out_size, void* d_ws, size_t ws_size,
                              hipStream_t stream)
{
    const float* img1 = (const float*)d_in[0];
    const float* img2 = (const float*)d_in[1];
    double* acc = (double*)d_ws;

    hipMemsetAsync(d_ws, 0, 256 * sizeof(double), stream);

    const int nch = in_sizes[0] / (IMG_W * IMG_H);      // 16*3 = 48
    dim3 grid(IMG_W / TW, IMG_H / TH, nch);             // 16 x 8 x 48
    ssim_tile_kernel<<<grid, 256, 0, stream>>>(img1, img2, acc);

    const double inv_total = 1.0 / (double)in_sizes[0];
    ssim_final_kernel<<<1, 256, 0, stream>>>(acc, (float*)d_out, inv_total);
}